// Round 9
// baseline (324.856 us; speedup 1.0000x reference)
//
#include <hip/hip_runtime.h>

#define IH 512
#define IW 512
#define NC 4
#define NB 32
#define RPT 4        // output rows per thread
#define NTILES 2048  // 4 (x) * 16 (y) * 32 (b)
#define NBLK2 512    // main grid; block B owns tiles B, B+512, B+1024, B+1536
#define TPB 4        // tiles per block (4 different images)

// native 4-float vector: __builtin_nontemporal_* requires a true vector type.
typedef float v4f __attribute__((ext_vector_type(4)));

// ---------------------------------------------------------------------------
// Kernel 0: zero the 32 per-image tile counters (ws is poisoned).
// ---------------------------------------------------------------------------
__global__ void init_cnt(unsigned int* __restrict__ cnt) {
    if (threadIdx.x < NB) cnt[threadIdx.x] = 0u;
}

// ---------------------------------------------------------------------------
// Load one input row segment (8 cols: w-2 .. w+5) into registers.
// Zero-fill OOB rows/cols (conv zero padding). w % 4 == 0.
// ---------------------------------------------------------------------------
__device__ __forceinline__ void load_row8(const float* __restrict__ xc, int hh,
                                          int w, bool v0, bool v2,
                                          float* __restrict__ dst) {
    if (hh < 0 || hh >= IH) {
        #pragma unroll
        for (int j = 0; j < 8; ++j) dst[j] = 0.f;
        return;
    }
    const float* rowp = xc + (size_t)hh * IW + w;
    float2 a  = v0 ? *(const float2*)(rowp - 2) : float2{0.f, 0.f};
    float4 bb =      *(const float4*)(rowp);
    float2 cc = v2 ? *(const float2*)(rowp + 4) : float2{0.f, 0.f};
    dst[0] = a.x;  dst[1] = a.y;
    dst[2] = bb.x; dst[3] = bb.y; dst[4] = bb.z; dst[5] = bb.w;
    dst[6] = cc.x; dst[7] = cc.y;
}

// ---------------------------------------------------------------------------
// Compute one 128x32 tile's responses for this thread's 4x4 patch.
// Tile id t -> (tx, ty, b): tx = t & 3, ty = (t>>2) & 15, b = t >> 6.
// ---------------------------------------------------------------------------
__device__ __forceinline__ void compute_tile(const float* __restrict__ x,
                                             int t, int qx, int tyg,
                                             float (&resp)[RPT][4]) {
    const int tx    = t & 3;
    const int ty    = (t >> 2) & 15;
    const int b     = t >> 6;
    const int w     = tx * 128 + qx * 4;
    const int hbase = ty * (8 * RPT) + tyg * RPT;

    const bool v0 = (w >= 4);
    const bool v2 = (w <= IW - 8);

    #pragma unroll
    for (int k = 0; k < RPT; ++k)
        #pragma unroll
        for (int j = 0; j < 4; ++j) resp[k][j] = 0.f;

    const float* xb = x + (size_t)b * NC * IH * IW;

    #pragma unroll 1
    for (int c = 0; c < NC; ++c) {
        const float* xc = xb + (size_t)c * IH * IW;

        // full window: rows hbase-2 .. hbase+5 (8 rows x 8 cols)
        float r[RPT + 4][8];
        #pragma unroll
        for (int rr = 0; rr < RPT + 4; ++rr)
            load_row8(xc, hbase - 2 + rr, w, v0, v2, r[rr]);

        #pragma unroll
        for (int k = 0; k < RPT; ++k) {
            const float* rm2 = r[k + 0];
            const float* rm1 = r[k + 1];
            const float* r0c = r[k + 2];
            const float* rp1 = r[k + 3];
            const float* rp2 = r[k + 4];

            #pragma unroll
            for (int j = 0; j < 4; ++j) {
                const int i = 2 + j;
                const float c0     = r0c[i];
                const float cross1 = rm1[i] + rp1[i] + r0c[i - 1] + r0c[i + 1];
                const float e3     = cross1 - 4.f * c0;
                const float ring   = rm2[i] + rp2[i] + r0c[i - 2] + r0c[i + 2]
                                   + rm1[i - 1] + rm1[i + 1]
                                   + rp1[i - 1] + rp1[i + 1];
                const float e5     = 16.f * c0 - 2.f * cross1 - ring;
                const float rc     = fmaxf(fabsf(e3), fabsf(e5));
                resp[k][j] = fmaxf(resp[k][j], rc);
            }
        }
    }
}

// ---------------------------------------------------------------------------
// Kernel 1: fully-fused edge + normalize via per-image spin counters, on a
// NORMAL launch (cooperative codegen caps VGPR at ~52-56 and serializes the
// load window — R4/R7). Block B computes 4 tiles of 4 DIFFERENT images,
// keeps responses in registers, publishes per-tile min/max + RELEASE-
// increments the image counter, spins until each image's 64 tiles are in,
// then normalizes from registers and stores out exactly once (nontemporal).
// Deadlock-safe: __launch_bounds__(256,2) caps VGPR at 256 (est ~160) ->
// >=2 blocks/CU -> all 512 blocks co-resident regardless of dispatch order.
// Eliminates vs R8: unnorm out write + norm kernel's read + one launch gap.
// ---------------------------------------------------------------------------
__global__ __launch_bounds__(256, 2) void edge_fused(
        const float* __restrict__ x, float* __restrict__ out,
        float* __restrict__ slotmin, float* __restrict__ slotmax,
        unsigned int* __restrict__ cnt) {
    const int qx  = threadIdx.x & 31;   // quad index along w (0..31)
    const int tyg = threadIdx.x >> 5;   // thread row group (0..7)
    const int B   = blockIdx.x;

    __shared__ float smin[4], smax[4];
    __shared__ float snorm[TPB][2];     // per-tile-slot {vmin, inv}

    float resp[TPB][RPT][4];

    // ---- compute 4 tiles, publish per-tile min/max ----
    #pragma unroll
    for (int s = 0; s < TPB; ++s) {
        const int t = B + s * NBLK2;
        compute_tile(x, t, qx, tyg, resp[s]);

        float lmin = resp[s][0][0], lmax = resp[s][0][0];
        #pragma unroll
        for (int k = 0; k < RPT; ++k)
            #pragma unroll
            for (int j = 0; j < 4; ++j) {
                lmin = fminf(lmin, resp[s][k][j]);
                lmax = fmaxf(lmax, resp[s][k][j]);
            }
        #pragma unroll
        for (int off = 32; off >= 1; off >>= 1) {
            lmin = fminf(lmin, __shfl_down(lmin, off));
            lmax = fmaxf(lmax, __shfl_down(lmax, off));
        }
        const int wave = threadIdx.x >> 6;
        const int lane = threadIdx.x & 63;
        if (lane == 0) { smin[wave] = lmin; smax[wave] = lmax; }
        __syncthreads();
        if (threadIdx.x == 0) {
            const float m0 = fminf(fminf(smin[0], smin[1]),
                                   fminf(smin[2], smin[3]));
            const float M0 = fmaxf(fmaxf(smax[0], smax[1]),
                                   fmaxf(smax[2], smax[3]));
            // agent-scope stores -> coherent point (cross-XCD visibility)
            __hip_atomic_store(&slotmin[t], m0, __ATOMIC_RELAXED,
                               __HIP_MEMORY_SCOPE_AGENT);
            __hip_atomic_store(&slotmax[t], M0, __ATOMIC_RELAXED,
                               __HIP_MEMORY_SCOPE_AGENT);
            __hip_atomic_fetch_add(&cnt[t >> 6], 1u, __ATOMIC_RELEASE,
                                   __HIP_MEMORY_SCOPE_AGENT);
        }
        __syncthreads();  // smin/smax reused next tile
    }

    // ---- spin until the 4 owned images are complete; reduce their slots ----
    // wave wv handles image of tile s = wv: img = (B>>6) + 8*wv.
    const int wv = threadIdx.x >> 6;    // 0..3 (exactly 4 waves)
    const int ln = threadIdx.x & 63;
    const int img = (B >> 6) + 8 * wv;
    if (ln == 0) {
        while (__hip_atomic_load(&cnt[img], __ATOMIC_ACQUIRE,
                                 __HIP_MEMORY_SCOPE_AGENT) < 64u)
            __builtin_amdgcn_s_sleep(2);
    }
    // lanes reconverge after lane 0's spin (wave lockstep); agent-scope slot
    // loads below bypass stale L1/L2 copies.
    float mn = __hip_atomic_load(&slotmin[img * 64 + ln], __ATOMIC_RELAXED,
                                 __HIP_MEMORY_SCOPE_AGENT);
    float mx = __hip_atomic_load(&slotmax[img * 64 + ln], __ATOMIC_RELAXED,
                                 __HIP_MEMORY_SCOPE_AGENT);
    #pragma unroll
    for (int off = 32; off >= 1; off >>= 1) {
        mn = fminf(mn, __shfl_down(mn, off));
        mx = fmaxf(mx, __shfl_down(mx, off));
    }
    if (ln == 0) {
        snorm[wv][0] = mn;
        snorm[wv][1] = 1.0f / (mx - mn + 1e-6f);
    }
    __syncthreads();

    // ---- normalize from registers, single nontemporal store ----
    #pragma unroll
    for (int s = 0; s < TPB; ++s) {
        const int t     = B + s * NBLK2;
        const float vmn = snorm[s][0];
        const float inv = snorm[s][1];
        const int tx    = t & 3;
        const int ty    = (t >> 2) & 15;
        const int b     = t >> 6;
        const int w     = tx * 128 + qx * 4;
        const int hbase = ty * (8 * RPT) + tyg * RPT;
        float* ob = out + ((size_t)b * IH + hbase) * IW + w;
        #pragma unroll
        for (int k = 0; k < RPT; ++k) {
            v4f o;
            o.x = (resp[s][k][0] - vmn) * inv;
            o.y = (resp[s][k][1] - vmn) * inv;
            o.z = (resp[s][k][2] - vmn) * inv;
            o.w = (resp[s][k][3] - vmn) * inv;
            __builtin_nontemporal_store(o, (v4f*)(ob + (size_t)k * IW));
        }
    }
}

extern "C" void kernel_launch(void* const* d_in, const int* in_sizes, int n_in,
                              void* d_out, int out_size, void* d_ws, size_t ws_size,
                              hipStream_t stream) {
    const float* x = (const float*)d_in[0];
    // k3 (d_in[1]) and k5 (d_in[2]) are compile-time constant stencils; baked in.
    float* out = (float*)d_out;
    float* slotmin = (float*)d_ws;                     // [NTILES] floats
    float* slotmax = slotmin + NTILES;                 // [NTILES] floats
    unsigned int* cnt = (unsigned int*)(slotmax + NTILES);  // [NB] u32

    hipLaunchKernelGGL(init_cnt, dim3(1), dim3(64), 0, stream, cnt);
    hipLaunchKernelGGL(edge_fused, dim3(NBLK2), dim3(256), 0, stream,
                       x, out, slotmin, slotmax, cnt);
}

// Round 10
// 214.301 us; speedup vs baseline: 1.5159x; 1.5159x over previous
//
#include <hip/hip_runtime.h>

#define IH 512
#define IW 512
#define NC 4
#define NB 32
#define RPT 4          // output rows per thread
#define NTILES 2048    // 4 (x) * 16 (y) * 32 (b)
#define TW 140         // LDS tile row stride in floats (35 x 16B chunks; 140*4=560B
                       // stride => wave halves land on different banks)
#define TROWS 36       // LDS tile rows (32 out + 4 halo)
#define CPR 35         // 16B chunks per row
#define NCHUNK (CPR * TROWS)   // 1260 chunks = 20160 B per channel tile

// native 4-float vector: __builtin_nontemporal_* requires a true vector type.
typedef float v4f __attribute__((ext_vector_type(4)));

// 16B of zeros in module global memory (NOT in poisoned ws): OOB staging lanes
// point their per-lane global source here.
__device__ __attribute__((aligned(16))) const float ZEROPAGE[4] = {0.f, 0.f, 0.f, 0.f};

typedef const __attribute__((address_space(1))) void gvoid_t;
typedef __attribute__((address_space(3))) void svoid_t;

// ---------------------------------------------------------------------------
// Stage one channel tile (rows R0-2..R0+33, cols C0-4..C0+135, zero-filled
// OOB) into LDS via global_load_lds width-16: 5 instructions per wave, each
// moving 1 KB wave-wide with no VGPR payload -> ~20 KB in flight per block.
// LDS dest is wave-uniform base + lane*16 (hardware adds the lane offset);
// the global source is per-lane. Chunk c -> row c/35, 16B block c%35.
// Last round overlaps round 3 (chunks 1004..1023 staged twice, same data).
// ---------------------------------------------------------------------------
__device__ __forceinline__ void stage_tile(const float* __restrict__ xc,
                                           float* __restrict__ lbuf,
                                           int R0, int C0, int wv, int ln) {
    const int bases[5] = {0, 256, 512, 768, NCHUNK - 256};
    #pragma unroll
    for (int rno = 0; rno < 5; ++rno) {
        const int chunk = bases[rno] + wv * 64 + ln;
        const int row   = chunk / CPR;
        const int blk   = chunk - row * CPR;
        const int gr    = R0 - 2 + row;
        const int gc    = C0 - 4 + blk * 4;
        const bool valid = (gr >= 0) & (gr < IH) & (gc >= 0) & (gc + 4 <= IW);
        const float* src = valid ? (xc + (size_t)gr * IW + gc) : ZEROPAGE;
        float* ldst = lbuf + (size_t)(bases[rno] + wv * 64) * 4;  // wave-uniform
        __builtin_amdgcn_global_load_lds((gvoid_t*)src, (svoid_t*)ldst, 16, 0, 0);
    }
}

// ---------------------------------------------------------------------------
// Read one 8-float window row (LDS cols qx*4+2 .. qx*4+9 == global w-2..w+5)
// as four float2 (8B-aligned; ds_read_b64 class).
// ---------------------------------------------------------------------------
__device__ __forceinline__ void load_wrow(const float* __restrict__ lds,
                                          int Lr, int qx, float* __restrict__ d) {
    const float* p = lds + Lr * TW + qx * 4 + 2;
    float2 a  = *(const float2*)(p + 0);
    float2 b  = *(const float2*)(p + 2);
    float2 c  = *(const float2*)(p + 4);
    float2 dd = *(const float2*)(p + 6);
    d[0] = a.x;  d[1] = a.y;  d[2] = b.x;  d[3] = b.y;
    d[4] = c.x;  d[5] = c.y;  d[6] = dd.x; d[7] = dd.y;
}

// ---------------------------------------------------------------------------
// Fused 3x3 + 5x5 stencil for one output row (4 cols), accumulate channel max.
// ---------------------------------------------------------------------------
__device__ __forceinline__ void stencil_row(const float* __restrict__ rm2,
                                            const float* __restrict__ rm1,
                                            const float* __restrict__ r0c,
                                            const float* __restrict__ rp1,
                                            const float* __restrict__ rp2,
                                            float* __restrict__ acc) {
    #pragma unroll
    for (int j = 0; j < 4; ++j) {
        const int i = 2 + j;
        const float c0     = r0c[i];
        const float cross1 = rm1[i] + rp1[i] + r0c[i - 1] + r0c[i + 1];
        const float e3     = cross1 - 4.f * c0;
        const float ring   = rm2[i] + rp2[i] + r0c[i - 2] + r0c[i + 2]
                           + rm1[i - 1] + rm1[i + 1]
                           + rp1[i - 1] + rp1[i + 1];
        const float e5     = 16.f * c0 - 2.f * cross1 - ring;
        const float rc     = fmaxf(fabsf(e3), fabsf(e5));
        acc[j] = fmaxf(acc[j], rc);
    }
}

// ---------------------------------------------------------------------------
// Kernel 1: LDS-staged edge kernel. Theory (R9 post-mortem): the register-
// window version is MLP-capped (~4.5 KB in flight/CU vs 9.2 KB needed for
// peak at ~900cyc HBM latency -> 2.4 TB/s observed). DMA staging moves 1 KB
// per instruction with zero VGPR payload -> HBM-saturating. Compute reads a
// rolling 5-row register window from LDS (static rotation, 40 VGPRs).
// Single buffer, 2 __syncthreads per channel; 4 blocks/CU stagger their
// stage/compute phases for cross-block overlap (m114).
// Epilogue identical to R8 (verified): unnorm out + per-tile min/max slots.
// ---------------------------------------------------------------------------
__global__ __launch_bounds__(256, 4) void edge_tiled(
        const float* __restrict__ x, float* __restrict__ out,
        float* __restrict__ slotmin, float* __restrict__ slotmax) {
    __shared__ float lds[NCHUNK * 4];   // 20160 B channel tile
    __shared__ float smin[4], smax[4];

    const int qx  = threadIdx.x & 31;   // quad index along w (0..31)
    const int tyg = (threadIdx.x >> 5) & 7;
    const int wv  = threadIdx.x >> 6;   // wave (0..3)
    const int ln  = threadIdx.x & 63;   // lane
    const int C0  = blockIdx.x * 128;
    const int R0  = blockIdx.y * 32;
    const int b   = blockIdx.z;

    const float* xb = x + (size_t)b * NC * IH * IW;

    float resp[RPT][4];
    #pragma unroll
    for (int k = 0; k < RPT; ++k)
        #pragma unroll
        for (int j = 0; j < 4; ++j) resp[k][j] = 0.f;

    #pragma unroll 1
    for (int c = 0; c < NC; ++c) {
        stage_tile(xb + (size_t)c * IH * IW, lds, R0, C0, wv, ln);
        __syncthreads();   // drains vmcnt -> DMA writes visible to all waves

        const int r0 = tyg * 4;   // first LDS row of this thread's window
        float w0[8], w1[8], w2[8], w3[8], w4[8];
        load_wrow(lds, r0 + 0, qx, w0);
        load_wrow(lds, r0 + 1, qx, w1);
        load_wrow(lds, r0 + 2, qx, w2);
        load_wrow(lds, r0 + 3, qx, w3);
        load_wrow(lds, r0 + 4, qx, w4);
        stencil_row(w0, w1, w2, w3, w4, resp[0]);
        load_wrow(lds, r0 + 5, qx, w0);          // rolling: reuse w0 as row +5
        stencil_row(w1, w2, w3, w4, w0, resp[1]);
        load_wrow(lds, r0 + 6, qx, w1);
        stencil_row(w2, w3, w4, w0, w1, resp[2]);
        load_wrow(lds, r0 + 7, qx, w2);
        stencil_row(w3, w4, w0, w1, w2, resp[3]);

        __syncthreads();   // all reads done before next channel overwrites lds
    }

    // ---- store unnormalized edge map (plain cached float4 stores: the
    //      tile-matched norm block re-reads this from the same XCD's L2) ----
    const int w     = C0 + qx * 4;
    const int hbase = R0 + tyg * 4;
    float* ob = out + ((size_t)b * IH + hbase) * IW + w;
    #pragma unroll
    for (int k = 0; k < RPT; ++k) {
        float4 o;
        o.x = resp[k][0]; o.y = resp[k][1]; o.z = resp[k][2]; o.w = resp[k][3];
        *(float4*)(ob + (size_t)k * IW) = o;
    }

    // ---- block min/max reduction -> per-tile slot (plain store) ----
    float lmin = resp[0][0], lmax = resp[0][0];
    #pragma unroll
    for (int k = 0; k < RPT; ++k)
        #pragma unroll
        for (int j = 0; j < 4; ++j) {
            lmin = fminf(lmin, resp[k][j]);
            lmax = fmaxf(lmax, resp[k][j]);
        }
    #pragma unroll
    for (int off = 32; off >= 1; off >>= 1) {
        lmin = fminf(lmin, __shfl_down(lmin, off));
        lmax = fmaxf(lmax, __shfl_down(lmax, off));
    }
    if (ln == 0) { smin[wv] = lmin; smax[wv] = lmax; }
    __syncthreads();
    if (threadIdx.x == 0) {
        const float m0 = fminf(fminf(smin[0], smin[1]), fminf(smin[2], smin[3]));
        const float M0 = fmaxf(fmaxf(smax[0], smax[1]), fmaxf(smax[2], smax[3]));
        const int slot = b * 64 + blockIdx.y * 4 + blockIdx.x;
        slotmin[slot] = m0;
        slotmax[slot] = M0;
    }
}

// ---------------------------------------------------------------------------
// Kernel 2: tile-matched in-place normalization (R8-verified, -3.4 us).
// Same grid geometry as edge -> same linear block index -> same XCD ->
// out-read hits the writing XCD's L2. Nontemporal final store.
// ---------------------------------------------------------------------------
__global__ __launch_bounds__(256) void norm_tile(
        float* __restrict__ out,
        const float* __restrict__ slotmin,
        const float* __restrict__ slotmax) {
    const int qx    = threadIdx.x & 31;
    const int tyg   = threadIdx.x >> 5;
    const int w     = blockIdx.x * 128 + qx * 4;
    const int hbase = blockIdx.y * (8 * RPT) + tyg * RPT;
    const int b     = blockIdx.z;

    __shared__ float sv[2];
    if (threadIdx.x < 64) {
        float mn = slotmin[b * 64 + threadIdx.x];
        float mx = slotmax[b * 64 + threadIdx.x];
        #pragma unroll
        for (int off = 32; off >= 1; off >>= 1) {
            mn = fminf(mn, __shfl_down(mn, off));
            mx = fmaxf(mx, __shfl_down(mx, off));
        }
        if (threadIdx.x == 0) { sv[0] = mn; sv[1] = mx; }
    }
    __syncthreads();
    const float vmin = sv[0];
    const float inv  = 1.0f / (sv[1] - vmin + 1e-6f);

    float* ob = out + ((size_t)b * IH + hbase) * IW + w;
    #pragma unroll
    for (int k = 0; k < RPT; ++k) {
        const float4 u = *(const float4*)(ob + (size_t)k * IW);
        v4f o;
        o.x = (u.x - vmin) * inv;
        o.y = (u.y - vmin) * inv;
        o.z = (u.z - vmin) * inv;
        o.w = (u.w - vmin) * inv;
        __builtin_nontemporal_store(o, (v4f*)(ob + (size_t)k * IW));
    }
}

extern "C" void kernel_launch(void* const* d_in, const int* in_sizes, int n_in,
                              void* d_out, int out_size, void* d_ws, size_t ws_size,
                              hipStream_t stream) {
    const float* x = (const float*)d_in[0];
    // k3 (d_in[1]) and k5 (d_in[2]) are compile-time constant stencils; baked in.
    float* out = (float*)d_out;
    float* slotmin = (float*)d_ws;        // [NTILES] floats
    float* slotmax = slotmin + NTILES;    // [NTILES] floats (16 KiB; ws ~512 MiB)

    hipLaunchKernelGGL(edge_tiled, dim3(4, 16, NB), dim3(256), 0, stream,
                       x, out, slotmin, slotmax);
    hipLaunchKernelGGL(norm_tile, dim3(4, 16, NB), dim3(256), 0, stream,
                       out, slotmin, slotmax);
}

// Round 11
// 214.074 us; speedup vs baseline: 1.5175x; 1.0011x over previous
//
#include <hip/hip_runtime.h>

#define IH 512
#define IW 512
#define NC 4
#define NB 32
#define RPT 4          // output rows per thread
#define NTILES 2048    // 4 (x) * 16 (y) * 32 (b)
#define TW 140         // LDS tile row stride in floats (35 x 16B chunks)
#define TROWS 36       // LDS tile rows (32 out + 4 halo)
#define CPR 35         // 16B chunks per row
#define NCHUNK (CPR * TROWS)   // 1260 chunks = 20160 B per channel tile
#define BUFSZ (NCHUNK * 4)     // floats per buffer

// native 4-float vector: __builtin_nontemporal_* requires a true vector type.
typedef float v4f __attribute__((ext_vector_type(4)));

// 16B of zeros in module global memory (NOT in poisoned ws): OOB staging lanes
// point their per-lane global source here.
__device__ __attribute__((aligned(16))) const float ZEROPAGE[4] = {0.f, 0.f, 0.f, 0.f};

typedef const __attribute__((address_space(1))) void gvoid_t;
typedef __attribute__((address_space(3))) void svoid_t;

// ---------------------------------------------------------------------------
// Stage one channel tile (rows R0-2..R0+33, cols C0-4..C0+135, zero-filled
// OOB) into an LDS buffer via global_load_lds width-16: 5 instructions per
// wave, each moving 1 KB wave-wide with no VGPR payload. LDS dest is
// wave-uniform base + lane*16; global source is per-lane (R10-verified).
// ---------------------------------------------------------------------------
__device__ __forceinline__ void stage_tile(const float* __restrict__ xc,
                                           float* __restrict__ lbuf,
                                           int R0, int C0, int wv, int ln) {
    const int bases[5] = {0, 256, 512, 768, NCHUNK - 256};
    #pragma unroll
    for (int rno = 0; rno < 5; ++rno) {
        const int chunk = bases[rno] + wv * 64 + ln;
        const int row   = chunk / CPR;
        const int blk   = chunk - row * CPR;
        const int gr    = R0 - 2 + row;
        const int gc    = C0 - 4 + blk * 4;
        const bool valid = (gr >= 0) & (gr < IH) & (gc >= 0) & (gc + 4 <= IW);
        const float* src = valid ? (xc + (size_t)gr * IW + gc) : ZEROPAGE;
        float* ldst = lbuf + (size_t)(bases[rno] + wv * 64) * 4;  // wave-uniform
        __builtin_amdgcn_global_load_lds((gvoid_t*)src, (svoid_t*)ldst, 16, 0, 0);
    }
}

// ---------------------------------------------------------------------------
// Read one 8-float window row (LDS cols qx*4+2 .. qx*4+9 == global w-2..w+5)
// as four float2 (8B-aligned).
// ---------------------------------------------------------------------------
__device__ __forceinline__ void load_wrow(const float* __restrict__ lds_,
                                          int Lr, int qx, float* __restrict__ d) {
    const float* p = lds_ + Lr * TW + qx * 4 + 2;
    float2 a  = *(const float2*)(p + 0);
    float2 b  = *(const float2*)(p + 2);
    float2 c  = *(const float2*)(p + 4);
    float2 dd = *(const float2*)(p + 6);
    d[0] = a.x;  d[1] = a.y;  d[2] = b.x;  d[3] = b.y;
    d[4] = c.x;  d[5] = c.y;  d[6] = dd.x; d[7] = dd.y;
}

// ---------------------------------------------------------------------------
// Fused 3x3 + 5x5 stencil for one output row (4 cols), accumulate channel max.
// ---------------------------------------------------------------------------
__device__ __forceinline__ void stencil_row(const float* __restrict__ rm2,
                                            const float* __restrict__ rm1,
                                            const float* __restrict__ r0c,
                                            const float* __restrict__ rp1,
                                            const float* __restrict__ rp2,
                                            float* __restrict__ acc) {
    #pragma unroll
    for (int j = 0; j < 4; ++j) {
        const int i = 2 + j;
        const float c0     = r0c[i];
        const float cross1 = rm1[i] + rp1[i] + r0c[i - 1] + r0c[i + 1];
        const float e3     = cross1 - 4.f * c0;
        const float ring   = rm2[i] + rp2[i] + r0c[i - 2] + r0c[i + 2]
                           + rm1[i - 1] + rm1[i + 1]
                           + rp1[i - 1] + rp1[i + 1];
        const float e5     = 16.f * c0 - 2.f * cross1 - ring;
        const float rc     = fmaxf(fabsf(e3), fabsf(e5));
        acc[j] = fmaxf(acc[j], rc);
    }
}

// ---------------------------------------------------------------------------
// Compute this thread's 4x4 patch from one staged channel buffer
// (rolling 5-row register window, static rotation).
// ---------------------------------------------------------------------------
__device__ __forceinline__ void compute_chan(const float* __restrict__ buf,
                                             int tyg, int qx,
                                             float (&resp)[RPT][4]) {
    const int r0 = tyg * 4;
    float w0[8], w1[8], w2[8], w3[8], w4[8];
    load_wrow(buf, r0 + 0, qx, w0);
    load_wrow(buf, r0 + 1, qx, w1);
    load_wrow(buf, r0 + 2, qx, w2);
    load_wrow(buf, r0 + 3, qx, w3);
    load_wrow(buf, r0 + 4, qx, w4);
    stencil_row(w0, w1, w2, w3, w4, resp[0]);
    load_wrow(buf, r0 + 5, qx, w0);
    stencil_row(w1, w2, w3, w4, w0, resp[1]);
    load_wrow(buf, r0 + 6, qx, w1);
    stencil_row(w2, w3, w4, w0, w1, resp[2]);
    load_wrow(buf, r0 + 7, qx, w2);
    stencil_row(w3, w4, w0, w1, w2, resp[3]);
}

// ---------------------------------------------------------------------------
// Kernel 1: LDS-staged edge kernel, DOUBLE-BUFFERED (2-phase pipeline).
// R10's single-buffer version serialized stage and compute (convoy: HBM
// bursts then idles -> only -2.2 us). Now: issue stage(c+1 -> nxt) FIRST,
// compute(c) from cur, then ONE __syncthreads() — its implicit vmcnt(0)
// lands after compute, when the DMA (issued a whole phase earlier) is
// already drained. Every block keeps ~20 KB outstanding -> HBM never idles.
// Buffer-overwrite hazard is covered by the previous iteration's barrier.
// LDS 2 x 20160 B + reduction arrays ~= 40.5 KB -> 4 blocks/CU (160 KiB).
// Epilogue identical to R8/R10 (verified).
// ---------------------------------------------------------------------------
__global__ __launch_bounds__(256, 4) void edge_tiled(
        const float* __restrict__ x, float* __restrict__ out,
        float* __restrict__ slotmin, float* __restrict__ slotmax) {
    __shared__ float lds[2 * BUFSZ];    // 2 x 20160 B channel tiles
    __shared__ float smin[4], smax[4];

    const int qx  = threadIdx.x & 31;   // quad index along w (0..31)
    const int tyg = (threadIdx.x >> 5) & 7;
    const int wv  = threadIdx.x >> 6;   // wave (0..3)
    const int ln  = threadIdx.x & 63;   // lane
    const int C0  = blockIdx.x * 128;
    const int R0  = blockIdx.y * 32;
    const int b   = blockIdx.z;

    const float* xb = x + (size_t)b * NC * IH * IW;

    float resp[RPT][4];
    #pragma unroll
    for (int k = 0; k < RPT; ++k)
        #pragma unroll
        for (int j = 0; j < 4; ++j) resp[k][j] = 0.f;

    // prologue: stage channel 0 into buffer 0
    stage_tile(xb, lds, R0, C0, wv, ln);
    __syncthreads();

    #pragma unroll
    for (int c = 0; c < NC; ++c) {
        float* cur = lds + (c & 1) * BUFSZ;
        float* nxt = lds + ((c + 1) & 1) * BUFSZ;
        if (c + 1 < NC)   // issue next channel's DMA BEFORE compute
            stage_tile(xb + (size_t)(c + 1) * IH * IW, nxt, R0, C0, wv, ln);
        compute_chan(cur, tyg, qx, resp);
        __syncthreads();  // drains DMA (already landed under compute) +
                          // protects cur from being overwritten next iter
    }

    // ---- store unnormalized edge map (plain cached float4 stores: the
    //      tile-matched norm block re-reads this from the same XCD's L2) ----
    const int w     = C0 + qx * 4;
    const int hbase = R0 + tyg * 4;
    float* ob = out + ((size_t)b * IH + hbase) * IW + w;
    #pragma unroll
    for (int k = 0; k < RPT; ++k) {
        float4 o;
        o.x = resp[k][0]; o.y = resp[k][1]; o.z = resp[k][2]; o.w = resp[k][3];
        *(float4*)(ob + (size_t)k * IW) = o;
    }

    // ---- block min/max reduction -> per-tile slot (plain store) ----
    float lmin = resp[0][0], lmax = resp[0][0];
    #pragma unroll
    for (int k = 0; k < RPT; ++k)
        #pragma unroll
        for (int j = 0; j < 4; ++j) {
            lmin = fminf(lmin, resp[k][j]);
            lmax = fmaxf(lmax, resp[k][j]);
        }
    #pragma unroll
    for (int off = 32; off >= 1; off >>= 1) {
        lmin = fminf(lmin, __shfl_down(lmin, off));
        lmax = fmaxf(lmax, __shfl_down(lmax, off));
    }
    if (ln == 0) { smin[wv] = lmin; smax[wv] = lmax; }
    __syncthreads();
    if (threadIdx.x == 0) {
        const float m0 = fminf(fminf(smin[0], smin[1]), fminf(smin[2], smin[3]));
        const float M0 = fmaxf(fmaxf(smax[0], smax[1]), fmaxf(smax[2], smax[3]));
        const int slot = b * 64 + blockIdx.y * 4 + blockIdx.x;
        slotmin[slot] = m0;
        slotmax[slot] = M0;
    }
}

// ---------------------------------------------------------------------------
// Kernel 2: tile-matched in-place normalization (R8-verified). Same grid
// geometry as edge -> same linear block index -> same XCD -> out-read hits
// the writing XCD's L2. Nontemporal final store.
// ---------------------------------------------------------------------------
__global__ __launch_bounds__(256) void norm_tile(
        float* __restrict__ out,
        const float* __restrict__ slotmin,
        const float* __restrict__ slotmax) {
    const int qx    = threadIdx.x & 31;
    const int tyg   = threadIdx.x >> 5;
    const int w     = blockIdx.x * 128 + qx * 4;
    const int hbase = blockIdx.y * (8 * RPT) + tyg * RPT;
    const int b     = blockIdx.z;

    __shared__ float sv[2];
    if (threadIdx.x < 64) {
        float mn = slotmin[b * 64 + threadIdx.x];
        float mx = slotmax[b * 64 + threadIdx.x];
        #pragma unroll
        for (int off = 32; off >= 1; off >>= 1) {
            mn = fminf(mn, __shfl_down(mn, off));
            mx = fmaxf(mx, __shfl_down(mx, off));
        }
        if (threadIdx.x == 0) { sv[0] = mn; sv[1] = mx; }
    }
    __syncthreads();
    const float vmin = sv[0];
    const float inv  = 1.0f / (sv[1] - vmin + 1e-6f);

    float* ob = out + ((size_t)b * IH + hbase) * IW + w;
    #pragma unroll
    for (int k = 0; k < RPT; ++k) {
        const float4 u = *(const float4*)(ob + (size_t)k * IW);
        v4f o;
        o.x = (u.x - vmin) * inv;
        o.y = (u.y - vmin) * inv;
        o.z = (u.z - vmin) * inv;
        o.w = (u.w - vmin) * inv;
        __builtin_nontemporal_store(o, (v4f*)(ob + (size_t)k * IW));
    }
}

extern "C" void kernel_launch(void* const* d_in, const int* in_sizes, int n_in,
                              void* d_out, int out_size, void* d_ws, size_t ws_size,
                              hipStream_t stream) {
    const float* x = (const float*)d_in[0];
    // k3 (d_in[1]) and k5 (d_in[2]) are compile-time constant stencils; baked in.
    float* out = (float*)d_out;
    float* slotmin = (float*)d_ws;        // [NTILES] floats
    float* slotmax = slotmin + NTILES;    // [NTILES] floats (16 KiB; ws ~512 MiB)

    hipLaunchKernelGGL(edge_tiled, dim3(4, 16, NB), dim3(256), 0, stream,
                       x, out, slotmin, slotmax);
    hipLaunchKernelGGL(norm_tile, dim3(4, 16, NB), dim3(256), 0, stream,
                       out, slotmin, slotmax);
}